// Round 6
// baseline (790.001 us; speedup 1.0000x reference)
//
#include <hip/hip_runtime.h>
#include <hip/hip_bf16.h>
#include <hip/hip_cooperative_groups.h>

namespace cg = cooperative_groups;

// GraphSAGE net on MI355X — r11: cooperative mega-kernel (r10 + coverage fix).
//   phase A: edge histograms (CSR blocks)  ||  weight cast (GEMM blocks)
//   phase B: partition scans               ||  GEMM1 chunk 0 (stage W once)
//   phase C: scatter to bins               ||  GEMM1 chunk 1
//   phase D: place (rp + u16 CSR)          ||  GEMM1 chunk 2
//   phase E: agg1   (all blocks)
//   phase F: GEMM2  (all blocks)
//   phase G: agg2   (all blocks)
// then separate gemm_out kernel (needs 64 KB LDS W1 stage).
// r10 BUG (absmax 0.59): single nws1 stride for all 3 GEMM1 column groups, but
// group sizes differ by 1 -> col group 2 (x@Ws.T) missed 4 tile-offsets/chunk.
// r11 fix: per-column cntc = (nGB+2-col1)/3, nws1 = cntc*4.

#define DD 128
#define SB 8               // 256 nodes per bucket
#define CH 4096            // edges per partition chunk
typedef unsigned short u16;
typedef __attribute__((ext_vector_type(8))) short short8;
typedef __attribute__((ext_vector_type(4))) float f32x4;

__device__ inline u16 f2bf(float f) {
    __hip_bfloat16 h = __float2bfloat16(f);
    u16 u;
    __builtin_memcpy(&u, &h, 2);
    return u;
}
__device__ inline unsigned pack2(float lo, float hi) {
    return (unsigned)f2bf(lo) | ((unsigned)f2bf(hi) << 16);
}
__device__ inline float bf_lo(unsigned u) { union { unsigned x; float f; } c; c.x = u << 16; return c.f; }
__device__ inline float bf_hi(unsigned u) { union { unsigned x; float f; } c; c.x = u & 0xffff0000u; return c.f; }

struct CastJobs {
    const float4* src[6];
    uint2* dst[6];
    int qstart[7];
};

struct MegaArgs {
    CastJobs jb;
    const float* x;
    const int* src0; const int* dst0;
    const int* src1; const int* dst1;
    int* hist0; int* hist1;
    int* bsum0; int* bsum1;
    unsigned* binned0; unsigned* binned1;
    int* rp0; int* rp1;
    u16* csr0; u16* csr1;
    const u16* wc1; const u16* wc2;
    u16* G1; u16* G2; u16* h1h; u16* h3h;
    const float* bl1; const float* bl2; const float* bsk;
    int E0, E1, N, nb, P, CSRB;
};

// streaming 16-row-tile GEMM over a staged 128x128 W tile (frag-swizzled LDS)
__device__ __forceinline__ void gemm_f32A(const float* x, const u16* Bs, u16* C,
                                          int lo, int hi, int wsid, int nws,
                                          int colBase, int lane, int NC) {
    int r = lane & 15, half = lane >> 4;
    const u16* bB = Bs + lane * 8;
    for (int tile = lo + wsid; tile < hi; tile += nws) {
        int rowA = (tile << 4) + r;
        const float4* Arow = (const float4*)x + (size_t)rowA * 32 + half * 2;
        short8 af[4];
#pragma unroll
        for (int kk = 0; kk < 4; ++kk) {
            float4 aa = Arow[kk * 8], bb = Arow[kk * 8 + 1];
            uint4 v = make_uint4(pack2(aa.x, aa.y), pack2(aa.z, aa.w),
                                 pack2(bb.x, bb.y), pack2(bb.z, bb.w));
            af[kk] = *(short8*)&v;
        }
        f32x4 acc[8];
#pragma unroll
        for (int i = 0; i < 8; ++i) acc[i] = (f32x4){0.f, 0.f, 0.f, 0.f};
#pragma unroll
        for (int kk = 0; kk < 4; ++kk)
#pragma unroll
            for (int ct = 0; ct < 8; ++ct) {
                short8 bf = *(const short8*)(bB + (ct * 4 + kk) * 512);
                acc[ct] = __builtin_amdgcn_mfma_f32_16x16x32_bf16(af[kk], bf, acc[ct], 0, 0, 0);
            }
#pragma unroll
        for (int ct = 0; ct < 8; ++ct) {
            int col = colBase + ct * 16 + r;
#pragma unroll
            for (int reg = 0; reg < 4; ++reg) {
                int row = (tile << 4) + half * 4 + reg;
                C[(size_t)row * NC + col] = f2bf(acc[ct][reg]);
            }
        }
    }
}

__device__ __forceinline__ void gemm_bf16A(const u16* A, const u16* Bs, u16* C,
                                           int lo, int hi, int wsid, int nws,
                                           int colBase, int lane, int NC) {
    int r = lane & 15, half = lane >> 4;
    const u16* bB = Bs + lane * 8;
    for (int tile = lo + wsid; tile < hi; tile += nws) {
        int rowA = (tile << 4) + r;
        const uint4* Arow = (const uint4*)A + (size_t)rowA * 16 + half;
        short8 af[4];
#pragma unroll
        for (int kk = 0; kk < 4; ++kk) {
            uint4 v = Arow[kk * 4];
            af[kk] = *(short8*)&v;
        }
        f32x4 acc[8];
#pragma unroll
        for (int i = 0; i < 8; ++i) acc[i] = (f32x4){0.f, 0.f, 0.f, 0.f};
#pragma unroll
        for (int kk = 0; kk < 4; ++kk)
#pragma unroll
            for (int ct = 0; ct < 8; ++ct) {
                short8 bf = *(const short8*)(bB + (ct * 4 + kk) * 512);
                acc[ct] = __builtin_amdgcn_mfma_f32_16x16x32_bf16(af[kk], bf, acc[ct], 0, 0, 0);
            }
#pragma unroll
        for (int ct = 0; ct < 8; ++ct) {
            int col = colBase + ct * 16 + r;
#pragma unroll
            for (int reg = 0; reg < 4; ++reg) {
                int row = (tile << 4) + half * 4 + reg;
                C[(size_t)row * NC + col] = f2bf(acc[ct][reg]);
            }
        }
    }
}

__global__ __launch_bounds__(256, 4) void mega_kernel(MegaArgs a) {
    cg::grid_group grid = cg::this_grid();
    __shared__ u16 Bs[32 * 512];   // 32 KB: GEMM W tile (per-block)
    __shared__ int Lc[256];
    __shared__ int Ls[256];
    const int t = threadIdx.x;
    const int b = blockIdx.x;
    const int G = gridDim.x;
    const int CSRB = a.CSRB;
    const bool isCSR = (b < CSRB);
    const int w = t >> 6, lane = t & 63;

    // ---------------- phase A: hist || cast ----------------
    if (isCSR) {
        for (int job = b; job < 2 * a.P; job += CSRB) {
            int arr = job / a.P, p = job % a.P;
            const int* dst = arr ? a.dst1 : a.dst0;
            int* hist = arr ? a.hist1 : a.hist0;
            int e = arr ? a.E1 : a.E0;
            Lc[t] = 0;
            __syncthreads();
            int base = p * CH, hi = min(base + CH, e);
            for (int i = base + t; i < hi; i += 256) atomicAdd(&Lc[dst[i] >> SB], 1);
            __syncthreads();
            if (t < a.nb) hist[t * a.P + p] = Lc[t];
            __syncthreads();
        }
    } else {
        int nC = G - CSRB;
        for (int q = (b - CSRB) * 256 + t; q < a.jb.qstart[6]; q += nC * 256) {
            int i = 0;
#pragma unroll
            for (int k = 1; k < 6; ++k) if (q >= a.jb.qstart[k]) i = k;
            int local = q - a.jb.qstart[i];
            float4 v = a.jb.src[i][local];
            a.jb.dst[i][local] = make_uint2(pack2(v.x, v.y), pack2(v.z, v.w));
        }
    }
    grid.sync();

    // GEMM1 work decomposition for non-CSR blocks (r11: per-column group count)
    const int nT1 = a.N >> 4;                     // 3125 row tiles
    const int nGB = G - CSRB;
    const int gj = b - CSRB;
    const int col1 = isCSR ? 0 : (gj % 3);
    const int cntc = (nGB + 2 - col1) / 3;        // blocks in THIS column group
    const int wsid1 = isCSR ? 0 : ((gj / 3) * 4 + w);
    const int nws1 = cntc * 4;
    const int c0 = 0, c1 = nT1 / 3, c2 = (2 * nT1) / 3, c3 = nT1;

    // ---------------- phase B: scan || GEMM1 stage + chunk0 ----------------
    if (isCSR) {
        for (int job = b; job < 2 * a.nb; job += CSRB) {
            int arr = job / a.nb, bb = job % a.nb;
            int* hist = arr ? a.hist1 : a.hist0;
            int* bsA = arr ? a.bsum1 : a.bsum0;
            int v = (t < a.P) ? hist[bb * a.P + t] : 0;
            Ls[t] = v;
            __syncthreads();
            for (int off = 1; off < 256; off <<= 1) {
                int u = (t >= off) ? Ls[t - off] : 0;
                __syncthreads();
                Ls[t] += u;
                __syncthreads();
            }
            if (t < a.P) hist[bb * a.P + t] = Ls[t] - v;
            if (t == 0) bsA[bb] = Ls[255];
            __syncthreads();
        }
    } else {
#pragma unroll
        for (int i = 0; i < 8; ++i) {             // stage wc1 tile (persists B..D)
            int id = t + 256 * i;
            int nrow = id >> 4, cc = id & 15;
            int f = ((nrow >> 4) << 2) | (cc >> 2);
            int dl = ((cc & 3) << 4) | (nrow & 15);
            *(uint4*)&Bs[(f * 64 + dl) * 8] = ((const uint4*)a.wc1)[(size_t)(col1 * 128 + nrow) * 16 + cc];
        }
        __syncthreads();
        gemm_f32A(a.x, Bs, a.G1, c0, c1, wsid1, nws1, col1 * 128, lane, 384);
    }
    grid.sync();

    // ---------------- phase C: scatter || GEMM1 chunk1 ----------------
    if (isCSR) {
        for (int job = b; job < 2 * a.P; job += CSRB) {
            int arr = job / a.P, p = job % a.P;
            const int* src = arr ? a.src1 : a.src0;
            const int* dst = arr ? a.dst1 : a.dst0;
            const int* hist = arr ? a.hist1 : a.hist0;
            const int* bsA = arr ? a.bsum1 : a.bsum0;
            unsigned* binned = arr ? a.binned1 : a.binned0;
            int e = arr ? a.E1 : a.E0;
            int v = (t < a.nb) ? bsA[t] : 0;      // in-block exclusive scan of bucket totals
            Ls[t] = v;
            __syncthreads();
            for (int off = 1; off < 256; off <<= 1) {
                int u = (t >= off) ? Ls[t - off] : 0;
                __syncthreads();
                Ls[t] += u;
                __syncthreads();
            }
            if (t < a.nb) Lc[t] = hist[t * a.P + p] + (Ls[t] - v);
            __syncthreads();
            int base = p * CH, hi = min(base + CH, e);
            for (int i = base + t; i < hi; i += 256) {
                int d = dst[i];
                int pos = atomicAdd(&Lc[d >> SB], 1);
                binned[pos] = ((unsigned)d << 16) | (unsigned)src[i];
            }
            __syncthreads();
        }
    } else {
        gemm_f32A(a.x, Bs, a.G1, c1, c2, wsid1, nws1, col1 * 128, lane, 384);
    }
    grid.sync();

    // ---------------- phase D: place || GEMM1 chunk2 ----------------
    if (isCSR) {
        for (int job = b; job < 2 * a.nb; job += CSRB) {
            int arr = job / a.nb, bb = job % a.nb;
            const unsigned* binned = arr ? a.binned1 : a.binned0;
            const int* bsA = arr ? a.bsum1 : a.bsum0;
            int* rp = arr ? a.rp1 : a.rp0;
            u16* csr = arr ? a.csr1 : a.csr0;
            int E = arr ? a.E1 : a.E0;
            Ls[t] = (t < a.nb) ? bsA[t] : 0;      // inclusive scan of bucket totals
            __syncthreads();
            for (int off = 1; off < 256; off <<= 1) {
                int u = (t >= off) ? Ls[t - off] : 0;
                __syncthreads();
                Ls[t] += u;
                __syncthreads();
            }
            int base = (bb > 0) ? Ls[bb - 1] : 0;
            int end = Ls[bb];
            if (bb == a.nb - 1 && t == 0) rp[a.N] = E;
            __syncthreads();
            Lc[t] = 0;
            __syncthreads();
            for (int i = base + t; i < end; i += 256)
                atomicAdd(&Lc[(binned[i] >> 16) & 255], 1);
            __syncthreads();
            int deg = Lc[t];
            Ls[t] = deg;
            __syncthreads();
            for (int off = 1; off < 256; off <<= 1) {
                int u = (t >= off) ? Ls[t - off] : 0;
                __syncthreads();
                Ls[t] += u;
                __syncthreads();
            }
            int gpos = base + Ls[t] - deg;
            int node = (bb << SB) + t;
            if (node < a.N) rp[node] = gpos;
            __syncthreads();
            Lc[t] = gpos;
            __syncthreads();
            for (int i = base + t; i < end; i += 256) {
                unsigned pk = binned[i];
                int ld = (pk >> 16) & 255;
                int pos = atomicAdd(&Lc[ld], 1);
                csr[pos] = (u16)(pk & 0xffffu);
            }
            __syncthreads();
        }
    } else {
        gemm_f32A(a.x, Bs, a.G1, c2, c3, wsid1, nws1, col1 * 128, lane, 384);
    }
    grid.sync();

    // ---------------- phase E: agg1 (all blocks) ----------------
    {
        int jobs = (a.N + 7) >> 3;
        int ln = t & 31;
        for (int job = b; job < jobs; job += G) {
            int g = (job << 3) + (t >> 5);
            if (g < a.N) {
                int start = a.rp0[g], end = a.rp0[g + 1];
                int d = end - start;
                const uint2* X2 = (const uint2*)a.G1;      // row stride 96 uint2
                float a0 = 0.f, a1 = 0.f, a2 = 0.f, a3 = 0.f;
                int e = start;
                for (; e + 3 < end; e += 4) {
                    int s0 = a.csr0[e], s1 = a.csr0[e + 1], s2 = a.csr0[e + 2], s3 = a.csr0[e + 3];
                    uint2 v0 = X2[(size_t)s0 * 96 + ln];
                    uint2 v1 = X2[(size_t)s1 * 96 + ln];
                    uint2 v2 = X2[(size_t)s2 * 96 + ln];
                    uint2 v3 = X2[(size_t)s3 * 96 + ln];
                    a0 += (bf_lo(v0.x) + bf_lo(v1.x)) + (bf_lo(v2.x) + bf_lo(v3.x));
                    a1 += (bf_hi(v0.x) + bf_hi(v1.x)) + (bf_hi(v2.x) + bf_hi(v3.x));
                    a2 += (bf_lo(v0.y) + bf_lo(v1.y)) + (bf_lo(v2.y) + bf_lo(v3.y));
                    a3 += (bf_hi(v0.y) + bf_hi(v1.y)) + (bf_hi(v2.y) + bf_hi(v3.y));
                }
                for (; e < end; ++e) {
                    uint2 v0 = X2[(size_t)a.csr0[e] * 96 + ln];
                    a0 += bf_lo(v0.x); a1 += bf_hi(v0.x);
                    a2 += bf_lo(v0.y); a3 += bf_hi(v0.y);
                }
                float sc = 1.0f / (float)max(d, 1);
                uint2 m = X2[(size_t)g * 96 + 32 + ln];    // G1M
                float4 bv = ((const float4*)a.bl1)[ln];
                uint2 r;
                r.x = pack2(a0 * sc + bf_lo(m.x) + bv.x, a1 * sc + bf_hi(m.x) + bv.y);
                r.y = pack2(a2 * sc + bf_lo(m.y) + bv.z, a3 * sc + bf_hi(m.y) + bv.w);
                ((uint2*)a.h1h)[(size_t)g * 32 + ln] = r;
            }
        }
    }
    grid.sync();

    // ---------------- phase F: GEMM2 (all blocks) ----------------
    {
        int col = b & 1;
#pragma unroll
        for (int i = 0; i < 8; ++i) {             // stage wc2 tile
            int id = t + 256 * i;
            int nrow = id >> 4, cc = id & 15;
            int f = ((nrow >> 4) << 2) | (cc >> 2);
            int dl = ((cc & 3) << 4) | (nrow & 15);
            *(uint4*)&Bs[(f * 64 + dl) * 8] = ((const uint4*)a.wc2)[(size_t)(col * 128 + nrow) * 16 + cc];
        }
        __syncthreads();
        int rg = b >> 1;
        int wsid = rg * 4 + w;
        int nws = (G >> 1) * 4;
        gemm_bf16A(a.h1h, Bs, a.G2, 0, nT1, wsid, nws, col * 128, lane, 256);
    }
    grid.sync();

    // ---------------- phase G: agg2 (all blocks) ----------------
    {
        int jobs = (a.N + 7) >> 3;
        int ln = t & 31;
        for (int job = b; job < jobs; job += G) {
            int g = (job << 3) + (t >> 5);
            if (g < a.N) {
                int start = a.rp1[g], end = a.rp1[g + 1];
                int d = end - start;
                const uint2* X2 = (const uint2*)a.G2;      // row stride 64 uint2
                float a0 = 0.f, a1 = 0.f, a2 = 0.f, a3 = 0.f;
                int e = start;
                for (; e + 3 < end; e += 4) {
                    int s0 = a.csr1[e], s1 = a.csr1[e + 1], s2 = a.csr1[e + 2], s3 = a.csr1[e + 3];
                    uint2 v0 = X2[(size_t)s0 * 64 + ln];
                    uint2 v1 = X2[(size_t)s1 * 64 + ln];
                    uint2 v2 = X2[(size_t)s2 * 64 + ln];
                    uint2 v3 = X2[(size_t)s3 * 64 + ln];
                    a0 += (bf_lo(v0.x) + bf_lo(v1.x)) + (bf_lo(v2.x) + bf_lo(v3.x));
                    a1 += (bf_hi(v0.x) + bf_hi(v1.x)) + (bf_hi(v2.x) + bf_hi(v3.x));
                    a2 += (bf_lo(v0.y) + bf_lo(v1.y)) + (bf_lo(v2.y) + bf_lo(v3.y));
                    a3 += (bf_hi(v0.y) + bf_hi(v1.y)) + (bf_hi(v2.y) + bf_hi(v3.y));
                }
                for (; e < end; ++e) {
                    uint2 v0 = X2[(size_t)a.csr1[e] * 64 + ln];
                    a0 += bf_lo(v0.x); a1 += bf_hi(v0.x);
                    a2 += bf_lo(v0.y); a3 += bf_hi(v0.y);
                }
                float sc = 1.0f / (float)max(d, 1);
                uint2 m2 = X2[(size_t)g * 64 + 32 + ln];                    // G2R
                uint2 m1 = ((const uint2*)a.G1)[(size_t)g * 96 + 64 + ln];  // G1R
                float4 cb = ((const float4*)a.bl2)[ln];
                float4 sb = ((const float4*)a.bsk)[ln];
                uint2 r;
                r.x = pack2(a0 * sc + bf_lo(m2.x) + bf_lo(m1.x) + cb.x + sb.x,
                            a1 * sc + bf_hi(m2.x) + bf_hi(m1.x) + cb.y + sb.y);
                r.y = pack2(a2 * sc + bf_lo(m2.y) + bf_lo(m1.y) + cb.z + sb.z,
                            a3 * sc + bf_hi(m2.y) + bf_hi(m1.y) + cb.w + sb.w);
                ((uint2*)a.h3h)[(size_t)g * 32 + ln] = r;
            }
        }
    }
}

// ---------------- fused MLP head: out = relu(h3@W1.T + b1) @ W2.T + b2 ----------------
__global__ __launch_bounds__(256) void gemm_out_kernel(const u16* __restrict__ h3,
                                                       const u16* __restrict__ W1,
                                                       const float* __restrict__ b1,
                                                       const float* __restrict__ W2,
                                                       const float* __restrict__ b2,
                                                       float* __restrict__ out, int M) {
    __shared__ u16 Bs[64 * 512];   // 64 KB
    __shared__ float w2s[3 * 256];
    __shared__ float b1s[256];
    const int t = threadIdx.x;
#pragma unroll
    for (int i = 0; i < 16; ++i) {
        int id = t + 256 * i;
        int nrow = id >> 4, cc = id & 15;
        int f = ((nrow >> 4) << 2) | (cc >> 2);
        int dl = ((cc & 3) << 4) | (nrow & 15);
        *(uint4*)&Bs[(f * 64 + dl) * 8] = ((const uint4*)W1)[(size_t)nrow * 16 + cc];
    }
    for (int i = t; i < 768; i += 256) w2s[i] = W2[i];
    b1s[t] = b1[t];
    __syncthreads();
    const int w = t >> 6, lane = t & 63, r = lane & 15, half = lane >> 4;
    const int nTiles = M >> 4;
    const int nWaves = gridDim.x * 4;
    const u16* bB = &Bs[lane * 8];
    float c0 = b2[0], c1 = b2[1], c2 = b2[2];
    for (int tile = blockIdx.x * 4 + w; tile < nTiles; tile += nWaves) {
        int rowA = (tile << 4) + r;
        const uint4* Arow = (const uint4*)h3 + (size_t)rowA * 16 + half;
        short8 af[4];
#pragma unroll
        for (int kk = 0; kk < 4; ++kk) {
            uint4 v = Arow[kk * 4];
            af[kk] = *(short8*)&v;
        }
        f32x4 acc[16];
#pragma unroll
        for (int i = 0; i < 16; ++i) acc[i] = (f32x4){0.f, 0.f, 0.f, 0.f};
#pragma unroll
        for (int kk = 0; kk < 4; ++kk)
#pragma unroll
            for (int ct = 0; ct < 16; ++ct) {
                short8 bf = *(const short8*)(bB + (ct * 4 + kk) * 512);
                acc[ct] = __builtin_amdgcn_mfma_f32_16x16x32_bf16(af[kk], bf, acc[ct], 0, 0, 0);
            }
        float p[4][3] = {{0.f, 0.f, 0.f}, {0.f, 0.f, 0.f}, {0.f, 0.f, 0.f}, {0.f, 0.f, 0.f}};
#pragma unroll
        for (int ct = 0; ct < 16; ++ct) {
            int col = ct * 16 + r;
            float bv = b1s[col];
            float w0 = w2s[col], w1 = w2s[256 + col], w2v = w2s[512 + col];
#pragma unroll
            for (int reg = 0; reg < 4; ++reg) {
                float h4 = fmaxf(acc[ct][reg] + bv, 0.f);
                p[reg][0] += h4 * w0;
                p[reg][1] += h4 * w1;
                p[reg][2] += h4 * w2v;
            }
        }
#pragma unroll
        for (int m = 1; m < 16; m <<= 1)
#pragma unroll
            for (int reg = 0; reg < 4; ++reg) {
                p[reg][0] += __shfl_xor(p[reg][0], m);
                p[reg][1] += __shfl_xor(p[reg][1], m);
                p[reg][2] += __shfl_xor(p[reg][2], m);
            }
        if (r == 0) {
#pragma unroll
            for (int reg = 0; reg < 4; ++reg) {
                int row = (tile << 4) + half * 4 + reg;
                out[(size_t)row * 3 + 0] = p[reg][0] + c0;
                out[(size_t)row * 3 + 1] = p[reg][1] + c1;
                out[(size_t)row * 3 + 2] = p[reg][2] + c2;
            }
        }
    }
}

extern "C" void kernel_launch(void* const* d_in, const int* in_sizes, int n_in,
                              void* d_out, int out_size, void* d_ws, size_t ws_size,
                              hipStream_t stream) {
    const float* x   = (const float*)d_in[0];
    const int*   ei0 = (const int*)d_in[1];
    const int*   ei1 = (const int*)d_in[2];
    const float* Wl1 = (const float*)d_in[3];
    const float* bl1 = (const float*)d_in[4];
    const float* Wr1 = (const float*)d_in[5];
    const float* Wl2 = (const float*)d_in[6];
    const float* bl2 = (const float*)d_in[7];
    const float* Wr2 = (const float*)d_in[8];
    const float* Wsk = (const float*)d_in[9];
    const float* bsk = (const float*)d_in[10];
    const float* W1  = (const float*)d_in[11];
    const float* b1  = (const float*)d_in[12];
    const float* W2  = (const float*)d_in[13];
    const float* b2  = (const float*)d_in[14];
    float* out = (float*)d_out;

    const int N  = in_sizes[0] / DD;   // 50000
    const int E0 = in_sizes[1] / 2;    // 800000
    const int E1 = in_sizes[2] / 2;
    const int H  = in_sizes[12];       // 256

    const int* src0 = ei0;      const int* dst0 = ei0 + E0;
    const int* src1 = ei1;      const int* dst1 = ei1 + E1;

    const int nb   = (N + 255) >> SB;                  // 196 buckets
    const int Emax = (E0 > E1) ? E0 : E1;
    const int P    = (Emax + CH - 1) / CH;             // 196 partitions (<= 256)

    // workspace carve (256B aligned)
    char* wp = (char*)d_ws;
    auto carve = [&](size_t bytes) { char* p = wp; wp += (bytes + 255) & ~(size_t)255; return p; };
    u16* G1   = (u16*)carve((size_t)N * 384 * 2);
    u16* G2   = (u16*)carve((size_t)N * 256 * 2);
    u16* h1h  = (u16*)carve((size_t)N * DD * 2);
    u16* h3h  = (u16*)carve((size_t)N * DD * 2);
    u16* wc1  = (u16*)carve((size_t)384 * DD * 2);   // [Wl1;Wr1;Ws]
    u16* wc2  = (u16*)carve((size_t)256 * DD * 2);   // [Wl2;Wr2]
    u16* w1h  = (u16*)carve((size_t)H * DD * 2);
    int* rp0  = (int*)carve((size_t)(N + 1) * 4);
    int* rp1  = (int*)carve((size_t)(N + 1) * 4);
    u16* csr0 = (u16*)carve((size_t)E0 * 2);
    u16* csr1 = (u16*)carve((size_t)E1 * 2);
    unsigned* binned0 = (unsigned*)carve((size_t)E0 * 4);
    unsigned* binned1 = (unsigned*)carve((size_t)E1 * 4);
    int* hist1_0 = (int*)carve((size_t)nb * P * 4);
    int* hist1_1 = (int*)carve((size_t)nb * P * 4);
    int* bsum0 = (int*)carve((size_t)nb * 4);
    int* bsum1 = (int*)carve((size_t)nb * 4);

    MegaArgs ma;
    const float* srcs[6] = {Wl1, Wr1, Wsk, Wl2, Wr2, W1};
    u16* dsts[6] = {wc1, wc1 + 128 * DD, wc1 + 256 * DD, wc2, wc2 + 128 * DD, w1h};
    int  cnts[6] = {DD * DD, DD * DD, DD * DD, DD * DD, DD * DD, H * DD};
    int q = 0;
    for (int i = 0; i < 6; ++i) {
        ma.jb.src[i] = (const float4*)srcs[i];
        ma.jb.dst[i] = (uint2*)dsts[i];
        ma.jb.qstart[i] = q;
        q += cnts[i] / 4;
    }
    ma.jb.qstart[6] = q;

    ma.x = x;
    ma.src0 = src0; ma.dst0 = dst0; ma.src1 = src1; ma.dst1 = dst1;
    ma.hist0 = hist1_0; ma.hist1 = hist1_1;
    ma.bsum0 = bsum0; ma.bsum1 = bsum1;
    ma.binned0 = binned0; ma.binned1 = binned1;
    ma.rp0 = rp0; ma.rp1 = rp1;
    ma.csr0 = csr0; ma.csr1 = csr1;
    ma.wc1 = wc1; ma.wc2 = wc2;
    ma.G1 = G1; ma.G2 = G2; ma.h1h = h1h; ma.h3h = h3h;
    ma.bl1 = bl1; ma.bl2 = bl2; ma.bsk = bsk;
    ma.E0 = E0; ma.E1 = E1; ma.N = N; ma.nb = nb; ma.P = P;

    int occ = 0;
    hipOccupancyMaxActiveBlocksPerMultiprocessor(&occ, mega_kernel, 256, 0);
    if (occ < 1) occ = 1;
    int G = occ * 256;                 // 256 CUs on MI355X
    if (G > 1024) G = 1024;
    ma.CSRB = (G >= 784) ? 2 * P : G / 2;

    void* kargs[] = { &ma };
    hipLaunchCooperativeKernel((void*)mega_kernel, dim3(G), dim3(256), kargs, 0, stream);

    // out = relu(h3@W1.T + b1) @ W2.T + b2   (h4 in registers)
    gemm_out_kernel<<<512, 256, 0, stream>>>(h3h, w1h, b1, W2, b2, out, N);
}

// Round 7
// 254.646 us; speedup vs baseline: 3.1024x; 3.1024x over previous
//
#include <hip/hip_runtime.h>
#include <hip/hip_bf16.h>

// GraphSAGE net on MI355X — r12: revert to r3 split-kernel structure (253.2 µs,
// best verified) + 8-way-deep agg gather unroll.
//   G1 = x @ [Wl1;Wr1;Ws].T   (fp32 A loaded direct-to-register, NC=384)
//   h1 = mean_nbr0(G1L) + G1M + bl1
//   G2 = h1 @ [Wl2;Wr2].T     (NC=256)
//   h3 = mean_nbr1(G2L) + G2R + G1R + bl2 + bs
//   out = relu(h3@W1.T+b1) @ W2.T + b2   (h4 never leaves registers)
// r11 post-mortem (mega-kernel, 790 µs, REFUTED): grid.sync spin traffic
// (~670 MB PMC'd FETCH+WRITE vs ~200 MB algorithmic) + one-size-fits-all
// occupancy (GEMM LDS capped gather phases at 16 waves/CU vs 32 standalone).
// Lesson: phases need heterogeneous occupancy; keep split kernels.
// r12 theory: aggs are LATENCY-bound (r4 divergence fix: no delta; r11 gather
// slowdown tracked occupancy) -> deepen MLP: 8-way unrolled gather (8x16B in
// flight per 16-lane group), 4-way mid, scalar tail.
// GEMM structure (r8): weights staged once per block in frag-swizzled LDS,
// B-frags hoisted to VGPRs, A-frags global->register, zero barriers/LDS in loop.
// CSR build = zero-global-atomic partitioned counting sort.

#define DD 128
#define SB 8               // 256 nodes per bucket
#define CH 4096            // edges per partition chunk
typedef unsigned short u16;
typedef __attribute__((ext_vector_type(8))) short short8;
typedef __attribute__((ext_vector_type(4))) float f32x4;

__device__ inline u16 f2bf(float f) {
    __hip_bfloat16 h = __float2bfloat16(f);
    u16 u;
    __builtin_memcpy(&u, &h, 2);
    return u;
}
__device__ inline unsigned pack2(float lo, float hi) {
    return (unsigned)f2bf(lo) | ((unsigned)f2bf(hi) << 16);
}
__device__ inline float bf_lo(unsigned u) { union { unsigned x; float f; } c; c.x = u << 16; return c.f; }
__device__ inline float bf_hi(unsigned u) { union { unsigned x; float f; } c; c.x = u & 0xffff0000u; return c.f; }

// ---------------- weight cast fp32 -> bf16 (concat slots) ----------------
struct CastJobs {
    const float4* src[6];
    uint2* dst[6];
    int qstart[7];
};

// ---------------- CSR build ----------------
// hist1 (+ fused weight cast): per-(bucket,partition) counts via LDS histogram.
// grid (P + CB, 2): blocks [0,P) do histogram; blocks [P, P+CB) at y==0 do cast.
__global__ __launch_bounds__(256) void hist1_kernel(CastJobs jb,
                                                    const int* __restrict__ dst0, int* __restrict__ h0,
                                                    const int* __restrict__ dst1, int* __restrict__ h1,
                                                    int e0, int e1, int nb, int P) {
    int bx = blockIdx.x;
    int t = threadIdx.x;
    if (bx >= P) {                              // fused cast (independent work)
        if (blockIdx.y == 0) {
            int q = (bx - P) * 256 + t;
            if (q < jb.qstart[6]) {
                int i = 0;
#pragma unroll
                for (int k = 1; k < 6; ++k) if (q >= jb.qstart[k]) i = k;
                int local = q - jb.qstart[i];
                float4 v = jb.src[i][local];
                jb.dst[i][local] = make_uint2(pack2(v.x, v.y), pack2(v.z, v.w));
            }
        }
        return;
    }
    int arr = blockIdx.y;
    const int* dst = arr ? dst1 : dst0;
    int* hist = arr ? h1 : h0;
    int e = arr ? e1 : e0;
    __shared__ int h[256];
    h[t] = 0;
    __syncthreads();
    int base = bx * CH;
    int hi = min(base + CH, e);
    for (int i = base + t; i < hi; i += 256) atomicAdd(&h[dst[i] >> SB], 1);
    __syncthreads();
    if (t < nb) hist[t * P + bx] = h[t];   // [bucket][partition]
}

// rowsum: bucket totals = sum_p hist1[b][p], parallel per bucket. grid (nb, 2).
__global__ __launch_bounds__(256) void rowsum_kernel(const int* __restrict__ h0, int* __restrict__ bs0,
                                                     const int* __restrict__ h1, int* __restrict__ bs1,
                                                     int P) {
    int arr = blockIdx.y;
    const int* hist = arr ? h1 : h0;
    int* bs = arr ? bs1 : bs0;
    int b = blockIdx.x;
    __shared__ int s[256];
    int t = threadIdx.x;
    s[t] = (t < P) ? hist[b * P + t] : 0;
    __syncthreads();
    for (int off = 128; off; off >>= 1) {
        if (t < off) s[t] += s[t + off];
        __syncthreads();
    }
    if (t == 0) bs[b] = s[0];
}

// bscan: exclusive scan of bucket totals -> bbase; rp[n]=E. grid(2).
__global__ __launch_bounds__(256) void bscan_kernel(const int* __restrict__ bs0, int* __restrict__ bb0, int* __restrict__ rp0, int e0,
                                                    const int* __restrict__ bs1, int* __restrict__ bb1, int* __restrict__ rp1, int e1,
                                                    int nb, int n) {
    int arr = blockIdx.x;
    const int* bsum = arr ? bs1 : bs0;
    int* bb = arr ? bb1 : bb0;
    int* rp = arr ? rp1 : rp0;
    int E = arr ? e1 : e0;
    __shared__ int s[256];
    int t = threadIdx.x;
    int v = (t < nb) ? bsum[t] : 0;
    s[t] = v;
    __syncthreads();
    for (int off = 1; off < 256; off <<= 1) {
        int u = (t >= off) ? s[t - off] : 0;
        __syncthreads();
        s[t] += u;
        __syncthreads();
    }
    if (t < nb) bb[t] = s[t] - v;
    if (t == 0) { bb[nb] = E; rp[n] = E; }
}

// offs: exclusive scan over partitions per bucket, + bbase[b]. In-place. grid (nb, 2).
__global__ __launch_bounds__(256) void offs_kernel(int* __restrict__ h0, const int* __restrict__ bb0,
                                                   int* __restrict__ h1, const int* __restrict__ bb1,
                                                   int P) {
    int arr = blockIdx.y;
    int* hist = arr ? h1 : h0;
    const int* bb = arr ? bb1 : bb0;
    int b = blockIdx.x;
    __shared__ int s[256];
    int t = threadIdx.x;
    int v = (t < P) ? hist[b * P + t] : 0;
    s[t] = v;
    __syncthreads();
    for (int off = 1; off < 256; off <<= 1) {
        int u = (t >= off) ? s[t - off] : 0;
        __syncthreads();
        s[t] += u;
        __syncthreads();
    }
    if (t < P) hist[b * P + t] = s[t] - v + bb[b];
}

// scatter1: chunk p -> bucket-contiguous binned via LDS bump counters, plain stores. grid (P, 2).
__global__ __launch_bounds__(256) void scatter1_kernel(
    const int* __restrict__ src0, const int* __restrict__ dst0, const int* __restrict__ h0, unsigned* __restrict__ binned0,
    const int* __restrict__ src1, const int* __restrict__ dst1, const int* __restrict__ h1, unsigned* __restrict__ binned1,
    int e0, int e1, int nb, int P) {
    int arr = blockIdx.y;
    const int* src = arr ? src1 : src0;
    const int* dst = arr ? dst1 : dst0;
    const int* hist = arr ? h1 : h0;
    unsigned* binned = arr ? binned1 : binned0;
    int e = arr ? e1 : e0;
    int p = blockIdx.x;
    __shared__ int cnt[256];
    int t = threadIdx.x;
    if (t < nb) cnt[t] = hist[t * P + p];
    __syncthreads();
    int base = p * CH;
    int hi = min(base + CH, e);
    for (int i = base + t; i < hi; i += 256) {
        int d = dst[i];
        int pos = atomicAdd(&cnt[d >> SB], 1);        // LDS atomic
        binned[pos] = ((unsigned)d << 16) | (unsigned)src[i];
    }
}

// place: per bucket: LDS node histogram + local scan -> rp[node] and dense u16 CSR. grid (nb, 2).
__global__ __launch_bounds__(256) void place_kernel(
    const unsigned* __restrict__ binned0, const int* __restrict__ bb0, int* __restrict__ rp0, u16* __restrict__ csr0,
    const unsigned* __restrict__ binned1, const int* __restrict__ bb1, int* __restrict__ rp1, u16* __restrict__ csr1,
    int n, int nb) {
    int arr = blockIdx.y;
    const unsigned* binned = arr ? binned1 : binned0;
    const int* bb = arr ? bb1 : bb0;
    int* rp = arr ? rp1 : rp0;
    u16* csr = arr ? csr1 : csr0;
    int b = blockIdx.x;
    __shared__ int cnt[256];
    __shared__ int s[256];
    int t = threadIdx.x;
    int base = bb[b], end = bb[b + 1];
    cnt[t] = 0;
    __syncthreads();
    for (int i = base + t; i < end; i += 256)
        atomicAdd(&cnt[(binned[i] >> 16) & 255], 1);   // LDS atomic
    __syncthreads();
    int deg = cnt[t];
    s[t] = deg;
    __syncthreads();
    for (int off = 1; off < 256; off <<= 1) {
        int u = (t >= off) ? s[t - off] : 0;
        __syncthreads();
        s[t] += u;
        __syncthreads();
    }
    int gpos = base + s[t] - deg;
    int node = (b << SB) + t;
    if (node < n) rp[node] = gpos;
    cnt[t] = gpos;
    __syncthreads();
    for (int i = base + t; i < end; i += 256) {
        unsigned pk = binned[i];
        int ld = (pk >> 16) & 255;
        int pos = atomicAdd(&cnt[ld], 1);              // LDS atomic
        csr[pos] = (u16)(pk & 0xffffu);
    }
}

// ---------------- agg layer 1: h1 = mean_nbr(G1[:, :128]) + G1[:,128:256] + bl1 ----------------
// 16 lanes per node; G1 row = 48 uint4 (384 bf16). r12: 8-way unrolled gather
// (8 x 16B loads in flight per 16-lane group), 4-way mid, scalar tail.
__global__ __launch_bounds__(256) void agg1_kernel(const u16* __restrict__ G1,
                                                   const u16* __restrict__ csr,
                                                   const int* __restrict__ rp,
                                                   const float* __restrict__ bl1,
                                                   u16* __restrict__ h1, int n) {
    int g = (blockIdx.x * 256 + threadIdx.x) >> 4;
    int lane = threadIdx.x & 15;
    if (g >= n) return;
    int start = rp[g], end = rp[g + 1];
    int d = end - start;
    const uint4* X4 = (const uint4*)G1;
    float acc[8] = {0.f, 0.f, 0.f, 0.f, 0.f, 0.f, 0.f, 0.f};
    int e = start;
    for (; e + 7 < end; e += 8) {
        int s0 = csr[e], s1 = csr[e + 1], s2 = csr[e + 2], s3 = csr[e + 3];
        int s4 = csr[e + 4], s5 = csr[e + 5], s6 = csr[e + 6], s7 = csr[e + 7];
        uint4 v0 = X4[(size_t)s0 * 48 + lane];
        uint4 v1 = X4[(size_t)s1 * 48 + lane];
        uint4 v2 = X4[(size_t)s2 * 48 + lane];
        uint4 v3 = X4[(size_t)s3 * 48 + lane];
        uint4 v4 = X4[(size_t)s4 * 48 + lane];
        uint4 v5 = X4[(size_t)s5 * 48 + lane];
        uint4 v6 = X4[(size_t)s6 * 48 + lane];
        uint4 v7 = X4[(size_t)s7 * 48 + lane];
        acc[0] += ((bf_lo(v0.x) + bf_lo(v1.x)) + (bf_lo(v2.x) + bf_lo(v3.x)))
                + ((bf_lo(v4.x) + bf_lo(v5.x)) + (bf_lo(v6.x) + bf_lo(v7.x)));
        acc[1] += ((bf_hi(v0.x) + bf_hi(v1.x)) + (bf_hi(v2.x) + bf_hi(v3.x)))
                + ((bf_hi(v4.x) + bf_hi(v5.x)) + (bf_hi(v6.x) + bf_hi(v7.x)));
        acc[2] += ((bf_lo(v0.y) + bf_lo(v1.y)) + (bf_lo(v2.y) + bf_lo(v3.y)))
                + ((bf_lo(v4.y) + bf_lo(v5.y)) + (bf_lo(v6.y) + bf_lo(v7.y)));
        acc[3] += ((bf_hi(v0.y) + bf_hi(v1.y)) + (bf_hi(v2.y) + bf_hi(v3.y)))
                + ((bf_hi(v4.y) + bf_hi(v5.y)) + (bf_hi(v6.y) + bf_hi(v7.y)));
        acc[4] += ((bf_lo(v0.z) + bf_lo(v1.z)) + (bf_lo(v2.z) + bf_lo(v3.z)))
                + ((bf_lo(v4.z) + bf_lo(v5.z)) + (bf_lo(v6.z) + bf_lo(v7.z)));
        acc[5] += ((bf_hi(v0.z) + bf_hi(v1.z)) + (bf_hi(v2.z) + bf_hi(v3.z)))
                + ((bf_hi(v4.z) + bf_hi(v5.z)) + (bf_hi(v6.z) + bf_hi(v7.z)));
        acc[6] += ((bf_lo(v0.w) + bf_lo(v1.w)) + (bf_lo(v2.w) + bf_lo(v3.w)))
                + ((bf_lo(v4.w) + bf_lo(v5.w)) + (bf_lo(v6.w) + bf_lo(v7.w)));
        acc[7] += ((bf_hi(v0.w) + bf_hi(v1.w)) + (bf_hi(v2.w) + bf_hi(v3.w)))
                + ((bf_hi(v4.w) + bf_hi(v5.w)) + (bf_hi(v6.w) + bf_hi(v7.w)));
    }
    for (; e + 3 < end; e += 4) {
        int s0 = csr[e], s1 = csr[e + 1], s2 = csr[e + 2], s3 = csr[e + 3];
        uint4 v0 = X4[(size_t)s0 * 48 + lane];
        uint4 v1 = X4[(size_t)s1 * 48 + lane];
        uint4 v2 = X4[(size_t)s2 * 48 + lane];
        uint4 v3 = X4[(size_t)s3 * 48 + lane];
        acc[0] += (bf_lo(v0.x) + bf_lo(v1.x)) + (bf_lo(v2.x) + bf_lo(v3.x));
        acc[1] += (bf_hi(v0.x) + bf_hi(v1.x)) + (bf_hi(v2.x) + bf_hi(v3.x));
        acc[2] += (bf_lo(v0.y) + bf_lo(v1.y)) + (bf_lo(v2.y) + bf_lo(v3.y));
        acc[3] += (bf_hi(v0.y) + bf_hi(v1.y)) + (bf_hi(v2.y) + bf_hi(v3.y));
        acc[4] += (bf_lo(v0.z) + bf_lo(v1.z)) + (bf_lo(v2.z) + bf_lo(v3.z));
        acc[5] += (bf_hi(v0.z) + bf_hi(v1.z)) + (bf_hi(v2.z) + bf_hi(v3.z));
        acc[6] += (bf_lo(v0.w) + bf_lo(v1.w)) + (bf_lo(v2.w) + bf_lo(v3.w));
        acc[7] += (bf_hi(v0.w) + bf_hi(v1.w)) + (bf_hi(v2.w) + bf_hi(v3.w));
    }
    for (; e < end; ++e) {
        uint4 v0 = X4[(size_t)csr[e] * 48 + lane];
        acc[0] += bf_lo(v0.x); acc[1] += bf_hi(v0.x);
        acc[2] += bf_lo(v0.y); acc[3] += bf_hi(v0.y);
        acc[4] += bf_lo(v0.z); acc[5] += bf_hi(v0.z);
        acc[6] += bf_lo(v0.w); acc[7] += bf_hi(v0.w);
    }
    float sc = 1.0f / (float)max(d, 1);
    uint4 m = X4[(size_t)g * 48 + 16 + lane];          // G1M (x@Wr1.T)
    const float4* bl = (const float4*)bl1;
    float4 ba = bl[lane * 2], bb = bl[lane * 2 + 1];
    uint4 r;
    r.x = pack2(acc[0] * sc + bf_lo(m.x) + ba.x, acc[1] * sc + bf_hi(m.x) + ba.y);
    r.y = pack2(acc[2] * sc + bf_lo(m.y) + ba.z, acc[3] * sc + bf_hi(m.y) + ba.w);
    r.z = pack2(acc[4] * sc + bf_lo(m.z) + bb.x, acc[5] * sc + bf_hi(m.z) + bb.y);
    r.w = pack2(acc[6] * sc + bf_lo(m.w) + bb.z, acc[7] * sc + bf_hi(m.w) + bb.w);
    ((uint4*)h1)[(size_t)g * 16 + lane] = r;
}

// ---------------- agg layer 2: h3 = mean_nbr(G2L) + G2R + G1R + bl2 + bs ----------------
__global__ __launch_bounds__(256) void agg2_kernel(const u16* __restrict__ G2,
                                                   const u16* __restrict__ G1,
                                                   const u16* __restrict__ csr,
                                                   const int* __restrict__ rp,
                                                   const float* __restrict__ bl2,
                                                   const float* __restrict__ bs,
                                                   u16* __restrict__ h3, int n) {
    int g = (blockIdx.x * 256 + threadIdx.x) >> 4;
    int lane = threadIdx.x & 15;
    if (g >= n) return;
    int start = rp[g], end = rp[g + 1];
    int d = end - start;
    const uint4* X4 = (const uint4*)G2;
    float acc[8] = {0.f, 0.f, 0.f, 0.f, 0.f, 0.f, 0.f, 0.f};
    int e = start;
    for (; e + 7 < end; e += 8) {
        int s0 = csr[e], s1 = csr[e + 1], s2 = csr[e + 2], s3 = csr[e + 3];
        int s4 = csr[e + 4], s5 = csr[e + 5], s6 = csr[e + 6], s7 = csr[e + 7];
        uint4 v0 = X4[(size_t)s0 * 32 + lane];
        uint4 v1 = X4[(size_t)s1 * 32 + lane];
        uint4 v2 = X4[(size_t)s2 * 32 + lane];
        uint4 v3 = X4[(size_t)s3 * 32 + lane];
        uint4 v4 = X4[(size_t)s4 * 32 + lane];
        uint4 v5 = X4[(size_t)s5 * 32 + lane];
        uint4 v6 = X4[(size_t)s6 * 32 + lane];
        uint4 v7 = X4[(size_t)s7 * 32 + lane];
        acc[0] += ((bf_lo(v0.x) + bf_lo(v1.x)) + (bf_lo(v2.x) + bf_lo(v3.x)))
                + ((bf_lo(v4.x) + bf_lo(v5.x)) + (bf_lo(v6.x) + bf_lo(v7.x)));
        acc[1] += ((bf_hi(v0.x) + bf_hi(v1.x)) + (bf_hi(v2.x) + bf_hi(v3.x)))
                + ((bf_hi(v4.x) + bf_hi(v5.x)) + (bf_hi(v6.x) + bf_hi(v7.x)));
        acc[2] += ((bf_lo(v0.y) + bf_lo(v1.y)) + (bf_lo(v2.y) + bf_lo(v3.y)))
                + ((bf_lo(v4.y) + bf_lo(v5.y)) + (bf_lo(v6.y) + bf_lo(v7.y)));
        acc[3] += ((bf_hi(v0.y) + bf_hi(v1.y)) + (bf_hi(v2.y) + bf_hi(v3.y)))
                + ((bf_hi(v4.y) + bf_hi(v5.y)) + (bf_hi(v6.y) + bf_hi(v7.y)));
        acc[4] += ((bf_lo(v0.z) + bf_lo(v1.z)) + (bf_lo(v2.z) + bf_lo(v3.z)))
                + ((bf_lo(v4.z) + bf_lo(v5.z)) + (bf_lo(v6.z) + bf_lo(v7.z)));
        acc[5] += ((bf_hi(v0.z) + bf_hi(v1.z)) + (bf_hi(v2.z) + bf_hi(v3.z)))
                + ((bf_hi(v4.z) + bf_hi(v5.z)) + (bf_hi(v6.z) + bf_hi(v7.z)));
        acc[6] += ((bf_lo(v0.w) + bf_lo(v1.w)) + (bf_lo(v2.w) + bf_lo(v3.w)))
                + ((bf_lo(v4.w) + bf_lo(v5.w)) + (bf_lo(v6.w) + bf_lo(v7.w)));
        acc[7] += ((bf_hi(v0.w) + bf_hi(v1.w)) + (bf_hi(v2.w) + bf_hi(v3.w)))
                + ((bf_hi(v4.w) + bf_hi(v5.w)) + (bf_hi(v6.w) + bf_hi(v7.w)));
    }
    for (; e + 3 < end; e += 4) {
        int s0 = csr[e], s1 = csr[e + 1], s2 = csr[e + 2], s3 = csr[e + 3];
        uint4 v0 = X4[(size_t)s0 * 32 + lane];
        uint4 v1 = X4[(size_t)s1 * 32 + lane];
        uint4 v2 = X4[(size_t)s2 * 32 + lane];
        uint4 v3 = X4[(size_t)s3 * 32 + lane];
        acc[0] += (bf_lo(v0.x) + bf_lo(v1.x)) + (bf_lo(v2.x) + bf_lo(v3.x));
        acc[1] += (bf_hi(v0.x) + bf_hi(v1.x)) + (bf_hi(v2.x) + bf_hi(v3.x));
        acc[2] += (bf_lo(v0.y) + bf_lo(v1.y)) + (bf_lo(v2.y) + bf_lo(v3.y));
        acc[3] += (bf_hi(v0.y) + bf_hi(v1.y)) + (bf_hi(v2.y) + bf_hi(v3.y));
        acc[4] += (bf_lo(v0.z) + bf_lo(v1.z)) + (bf_lo(v2.z) + bf_lo(v3.z));
        acc[5] += (bf_hi(v0.z) + bf_hi(v1.z)) + (bf_hi(v2.z) + bf_hi(v3.z));
        acc[6] += (bf_lo(v0.w) + bf_lo(v1.w)) + (bf_lo(v2.w) + bf_lo(v3.w));
        acc[7] += (bf_hi(v0.w) + bf_hi(v1.w)) + (bf_hi(v2.w) + bf_hi(v3.w));
    }
    for (; e < end; ++e) {
        uint4 v0 = X4[(size_t)csr[e] * 32 + lane];
        acc[0] += bf_lo(v0.x); acc[1] += bf_hi(v0.x);
        acc[2] += bf_lo(v0.y); acc[3] += bf_hi(v0.y);
        acc[4] += bf_lo(v0.z); acc[5] += bf_hi(v0.z);
        acc[6] += bf_lo(v0.w); acc[7] += bf_hi(v0.w);
    }
    float sc = 1.0f / (float)max(d, 1);
    uint4 m2 = X4[(size_t)g * 32 + 16 + lane];                    // G2R (h1@Wr2.T)
    uint4 m1 = ((const uint4*)G1)[(size_t)g * 48 + 32 + lane];    // G1R (x@Ws.T)
    const float4* c2 = (const float4*)bl2;
    const float4* cs = (const float4*)bs;
    float4 ba = c2[lane * 2], bb = c2[lane * 2 + 1];
    float4 sa = cs[lane * 2], sb = cs[lane * 2 + 1];
    uint4 r;
    r.x = pack2(acc[0] * sc + bf_lo(m2.x) + bf_lo(m1.x) + ba.x + sa.x,
                acc[1] * sc + bf_hi(m2.x) + bf_hi(m1.x) + ba.y + sa.y);
    r.y = pack2(acc[2] * sc + bf_lo(m2.y) + bf_lo(m1.y) + ba.z + sa.z,
                acc[3] * sc + bf_hi(m2.y) + bf_hi(m1.y) + ba.w + sa.w);
    r.z = pack2(acc[4] * sc + bf_lo(m2.z) + bf_lo(m1.z) + bb.x + sb.x,
                acc[5] * sc + bf_hi(m2.z) + bf_hi(m1.z) + bb.y + sb.y);
    r.w = pack2(acc[6] * sc + bf_lo(m2.w) + bf_lo(m1.w) + bb.z + sb.z,
                acc[7] * sc + bf_hi(m2.w) + bf_hi(m1.w) + bb.w + sb.w);
    ((uint4*)h3)[(size_t)g * 16 + lane] = r;
}

// ---------------- streaming MFMA GEMM: C = A @ W.T, bf16 out ----------------
// W tile (128 cols x K=128) staged ONCE per block in frag-swizzled LDS, then
// hoisted ONCE per wave into 128 VGPRs. A-frags load global->register.
// Zero barriers AND zero LDS in the tile loop. grid (blocksPerCol, NC/128).
template <bool F32A>
__global__ __launch_bounds__(256) void mfma_gemm(const void* __restrict__ Av,
                                                 const u16* __restrict__ W,
                                                 u16* __restrict__ C, int M, int NC) {
    __shared__ u16 Bs[32 * 512];   // 32 frags x 64 lanes x 8 shorts = 32 KB
    const int t = threadIdx.x;
    const int colBase = blockIdx.y * 128;
#pragma unroll
    for (int i = 0; i < 8; ++i) {               // stage 128x128 W tile, swizzled
        int id = t + 256 * i;                   // 0..2047
        int nrow = id >> 4, cc = id & 15;       // W row (col of C), k-chunk
        int f = ((nrow >> 4) << 2) | (cc >> 2); // frag = ct*4 + kk
        int dl = ((cc & 3) << 4) | (nrow & 15); // lane = half*16 + r
        *(uint4*)&Bs[(f * 64 + dl) * 8] = ((const uint4*)W)[(size_t)(colBase + nrow) * 16 + cc];
    }
    __syncthreads();
    const int w = t >> 6, lane = t & 63, r = lane & 15, half = lane >> 4;
    // hoist all 32 B-frags LDS -> VGPRs once per wave (loop-invariant)
    short8 bf[32];
#pragma unroll
    for (int f = 0; f < 32; ++f)
        bf[f] = *(const short8*)&Bs[(f * 64 + lane) * 8];
    const int nTiles = M >> 4;
    const int nWaves = gridDim.x * 4;
    for (int tile = blockIdx.x * 4 + w; tile < nTiles; tile += nWaves) {
        int rowA = (tile << 4) + r;
        short8 af[4];
        if (F32A) {
            const float4* Arow = (const float4*)Av + (size_t)rowA * 32 + half * 2;
#pragma unroll
            for (int kk = 0; kk < 4; ++kk) {
                float4 a = Arow[kk * 8], b = Arow[kk * 8 + 1];
                uint4 v = make_uint4(pack2(a.x, a.y), pack2(a.z, a.w),
                                     pack2(b.x, b.y), pack2(b.z, b.w));
                af[kk] = *(short8*)&v;
            }
        } else {
            const uint4* Arow = (const uint4*)Av + (size_t)rowA * 16 + half;
#pragma unroll
            for (int kk = 0; kk < 4; ++kk) {
                uint4 v = Arow[kk * 4];
                af[kk] = *(short8*)&v;
            }
        }
        f32x4 acc[8];
#pragma unroll
        for (int i = 0; i < 8; ++i) acc[i] = (f32x4){0.f, 0.f, 0.f, 0.f};
#pragma unroll
        for (int kk = 0; kk < 4; ++kk)
#pragma unroll
            for (int ct = 0; ct < 8; ++ct)
                acc[ct] = __builtin_amdgcn_mfma_f32_16x16x32_bf16(af[kk], bf[ct * 4 + kk], acc[ct], 0, 0, 0);
#pragma unroll
        for (int ct = 0; ct < 8; ++ct) {
            int col = colBase + ct * 16 + r;
#pragma unroll
            for (int reg = 0; reg < 4; ++reg) {
                int row = (tile << 4) + half * 4 + reg;
                C[(size_t)row * NC + col] = f2bf(acc[ct][reg]);
            }
        }
    }
}

// ---------------- fused MLP head: out = relu(h3@W1.T + b1) @ W2.T + b2 ----------------
// Streaming, W1 (256x128) staged once frag-swizzled (64 KB); h4 in registers.
__global__ __launch_bounds__(256) void gemm_out_kernel(const u16* __restrict__ h3,
                                                       const u16* __restrict__ W1,
                                                       const float* __restrict__ b1,
                                                       const float* __restrict__ W2,
                                                       const float* __restrict__ b2,
                                                       float* __restrict__ out, int M) {
    __shared__ u16 Bs[64 * 512];   // 64 frags x 64 lanes x 8 shorts = 64 KB
    __shared__ float w2s[3 * 256];
    __shared__ float b1s[256];
    const int t = threadIdx.x;
#pragma unroll
    for (int i = 0; i < 16; ++i) {
        int id = t + 256 * i;                   // 0..4095
        int nrow = id >> 4, cc = id & 15;
        int f = ((nrow >> 4) << 2) | (cc >> 2);
        int dl = ((cc & 3) << 4) | (nrow & 15);
        *(uint4*)&Bs[(f * 64 + dl) * 8] = ((const uint4*)W1)[(size_t)nrow * 16 + cc];
    }
    for (int i = t; i < 768; i += 256) w2s[i] = W2[i];
    b1s[t] = b1[t];
    __syncthreads();
    const int w = t >> 6, lane = t & 63, r = lane & 15, half = lane >> 4;
    const int nTiles = M >> 4;
    const int nWaves = gridDim.x * 4;
    const u16* bB = &Bs[lane * 8];
    float c0 = b2[0], c1 = b2[1], c2 = b2[2];
    for (int tile = blockIdx.x * 4 + w; tile < nTiles; tile += nWaves) {
        int rowA = (tile << 4) + r;
        const uint4* Arow = (const uint4*)h3 + (size_t)rowA * 16 + half;
        short8 af[4];
#pragma unroll
        for (int kk = 0; kk < 4; ++kk) {
            uint4 v = Arow[kk * 4];
            af[kk] = *(short8*)&v;
        }
        f32x4 acc[16];
#pragma unroll
        for (int i = 0; i < 16; ++i) acc[i] = (f32x4){0.f, 0.f, 0.f, 0.f};
#pragma unroll
        for (int kk = 0; kk < 4; ++kk)
#pragma unroll
            for (int ct = 0; ct < 16; ++ct) {
                short8 bf = *(const short8*)(bB + (ct * 4 + kk) * 512);
                acc[ct] = __builtin_amdgcn_mfma_f32_16x16x32_bf16(af[kk], bf, acc[ct], 0, 0, 0);
            }
        float p[4][3] = {{0.f, 0.f, 0.f}, {0.f, 0.f, 0.f}, {0.f, 0.f, 0.f}, {0.f, 0.f, 0.f}};
#pragma unroll
        for (int ct = 0; ct < 16; ++ct) {
            int col = ct * 16 + r;
            float bv = b1s[col];
            float w0 = w2s[col], w1 = w2s[256 + col], w2v = w2s[512 + col];
#pragma unroll
            for (int reg = 0; reg < 4; ++reg) {
                float h4 = fmaxf(acc[ct][reg] + bv, 0.f);
                p[reg][0] += h4 * w0;
                p[reg][1] += h4 * w1;
                p[reg][2] += h4 * w2v;
            }
        }
#pragma unroll
        for (int m = 1; m < 16; m <<= 1)
#pragma unroll
            for (int reg = 0; reg < 4; ++reg) {
                p[reg][0] += __shfl_xor(p[reg][0], m);
                p[reg][1] += __shfl_xor(p[reg][1], m);
                p[reg][2] += __shfl_xor(p[reg][2], m);
            }
        if (r == 0) {
#pragma unroll
            for (int reg = 0; reg < 4; ++reg) {
                int row = (tile << 4) + half * 4 + reg;
                out[(size_t)row * 3 + 0] = p[reg][0] + c0;
                out[(size_t)row * 3 + 1] = p[reg][1] + c1;
                out[(size_t)row * 3 + 2] = p[reg][2] + c2;
            }
        }
    }
}

extern "C" void kernel_launch(void* const* d_in, const int* in_sizes, int n_in,
                              void* d_out, int out_size, void* d_ws, size_t ws_size,
                              hipStream_t stream) {
    const float* x   = (const float*)d_in[0];
    const int*   ei0 = (const int*)d_in[1];
    const int*   ei1 = (const int*)d_in[2];
    const float* Wl1 = (const float*)d_in[3];
    const float* bl1 = (const float*)d_in[4];
    const float* Wr1 = (const float*)d_in[5];
    const float* Wl2 = (const float*)d_in[6];
    const float* bl2 = (const float*)d_in[7];
    const float* Wr2 = (const float*)d_in[8];
    const float* Wsk = (const float*)d_in[9];
    const float* bsk = (const float*)d_in[10];
    const float* W1  = (const float*)d_in[11];
    const float* b1  = (const float*)d_in[12];
    const float* W2  = (const float*)d_in[13];
    const float* b2  = (const float*)d_in[14];
    float* out = (float*)d_out;

    const int N  = in_sizes[0] / DD;   // 50000
    const int E0 = in_sizes[1] / 2;    // 800000
    const int E1 = in_sizes[2] / 2;
    const int H  = in_sizes[12];       // 256

    const int* src0 = ei0;      const int* dst0 = ei0 + E0;
    const int* src1 = ei1;      const int* dst1 = ei1 + E1;

    const int nb   = (N + 255) >> SB;                  // 196 buckets
    const int Emax = (E0 > E1) ? E0 : E1;
    const int P    = (Emax + CH - 1) / CH;             // 196 partitions (<= 256)

    // workspace carve (256B aligned)
    char* wp = (char*)d_ws;
    auto carve = [&](size_t bytes) { char* p = wp; wp += (bytes + 255) & ~(size_t)255; return p; };
    u16* G1   = (u16*)carve((size_t)N * 384 * 2);
    u16* G2   = (u16*)carve((size_t)N * 256 * 2);
    u16* h1h  = (u16*)carve((size_t)N * DD * 2);
    u16* h3h  = (u16*)carve((size_t)N * DD * 2);
    u16* wc1  = (u16*)carve((size_t)384 * DD * 2);   // [Wl1;Wr1;Ws]
    u16* wc2  = (u16*)carve((size_t)256 * DD * 2);   // [Wl2;Wr2]
    u16* w1h  = (u16*)carve((size_t)H * DD * 2);
    int* rp0  = (int*)carve((size_t)(N + 1) * 4);
    int* rp1  = (int*)carve((size_t)(N + 1) * 4);
    u16* csr0 = (u16*)carve((size_t)E0 * 2);
    u16* csr1 = (u16*)carve((size_t)E1 * 2);
    unsigned* binned0 = (unsigned*)carve((size_t)E0 * 4);
    unsigned* binned1 = (unsigned*)carve((size_t)E1 * 4);
    int* hist1_0 = (int*)carve((size_t)nb * P * 4);
    int* hist1_1 = (int*)carve((size_t)nb * P * 4);
    int* bsum0 = (int*)carve((size_t)nb * 4);
    int* bsum1 = (int*)carve((size_t)nb * 4);
    int* bb0 = (int*)carve((size_t)(nb + 1) * 4);
    int* bb1 = (int*)carve((size_t)(nb + 1) * 4);

    // weight cast into concat slots
    CastJobs jb;
    const float* srcs[6] = {Wl1, Wr1, Wsk, Wl2, Wr2, W1};
    u16* dsts[6] = {wc1, wc1 + 128 * DD, wc1 + 256 * DD, wc2, wc2 + 128 * DD, w1h};
    int  cnts[6] = {DD * DD, DD * DD, DD * DD, DD * DD, DD * DD, H * DD};
    int q = 0;
    for (int i = 0; i < 6; ++i) {
        jb.src[i] = (const float4*)srcs[i];
        jb.dst[i] = (uint2*)dsts[i];
        jb.qstart[i] = q;
        q += cnts[i] / 4;
    }
    jb.qstart[6] = q;
    const int CB = (q + 255) / 256;    // cast blocks fused into hist1

    const int gAgg = (N * 16 + 255) / 256;

    hist1_kernel<<<dim3(P + CB, 2), 256, 0, stream>>>(jb, dst0, hist1_0, dst1, hist1_1, E0, E1, nb, P);
    rowsum_kernel<<<dim3(nb, 2), 256, 0, stream>>>(hist1_0, bsum0, hist1_1, bsum1, P);
    bscan_kernel<<<2, 256, 0, stream>>>(bsum0, bb0, rp0, E0, bsum1, bb1, rp1, E1, nb, N);
    offs_kernel<<<dim3(nb, 2), 256, 0, stream>>>(hist1_0, bb0, hist1_1, bb1, P);
    scatter1_kernel<<<dim3(P, 2), 256, 0, stream>>>(src0, dst0, hist1_0, binned0,
                                                    src1, dst1, hist1_1, binned1, E0, E1, nb, P);
    place_kernel<<<dim3(nb, 2), 256, 0, stream>>>(binned0, bb0, rp0, csr0,
                                                  binned1, bb1, rp1, csr1, N, nb);

    // G1 = x @ [Wl1;Wr1;Ws].T  (fp32 A direct-to-register, NC=384)
    mfma_gemm<true><<<dim3(320, 3), 256, 0, stream>>>(x, wc1, G1, N, 384);
    // h1 = mean_nbr0(G1L) + G1M + bl1
    agg1_kernel<<<gAgg, 256, 0, stream>>>(G1, csr0, rp0, bl1, h1h, N);
    // G2 = h1 @ [Wl2;Wr2].T  (NC=256)
    mfma_gemm<false><<<dim3(320, 2), 256, 0, stream>>>(h1h, wc2, G2, N, 256);
    // h3 = mean_nbr1(G2L) + G2R + G1R + bl2 + bs
    agg2_kernel<<<gAgg, 256, 0, stream>>>(G2, G1, csr1, rp1, bl2, bsk, h3h, N);
    // out = relu(h3@W1.T + b1) @ W2.T + b2   (h4 in registers)
    gemm_out_kernel<<<512, 256, 0, stream>>>(h3h, w1h, b1, W2, b2, out, N);
}